// Round 3
// baseline (203.253 us; speedup 1.0000x reference)
//
#include <hip/hip_runtime.h>
#include <hip/hip_bf16.h>
#include <stdint.h>

typedef __bf16 bf16_t;
typedef __bf16 bf16x8 __attribute__((ext_vector_type(8)));
typedef __bf16 bf16x4 __attribute__((ext_vector_type(4)));
typedef float  f32x4  __attribute__((ext_vector_type(4)));

#define AS_GLOBAL __attribute__((address_space(1)))
#define AS_LDS    __attribute__((address_space(3)))
#define VMW(N) asm volatile("s_waitcnt vmcnt(" #N ")" ::: "memory")

static constexpr int CCH   = 256;
static constexpr int HP    = 34;
static constexpr int PLANE = HP * HP;   // 1156 padded pixels per image

// ---------------- BN parameter folding ----------------
__global__ void prep_params_k(const float* g1, const float* b1, const float* m1, const float* v1,
                              const float* g2, const float* b2, const float* m2, const float* v2,
                              float* prm) {
  int i = threadIdx.x;
  float i1 = g1[i] * rsqrtf(v1[i] + 1e-5f);
  prm[i]       = i1;
  prm[256 + i] = b1[i] - m1[i] * i1;
  float i2 = g2[i] * rsqrtf(v2[i] + 1e-5f);
  prm[512 + i] = i2;
  prm[768 + i] = b2[i] - m2[i] * i2;
}

// ---------------- masked weights -> bf16, [khw][co][ci] ----------------
__global__ __launch_bounds__(256) void prep_weights_k(const float* __restrict__ w,
                                                      const float* __restrict__ msk,
                                                      bf16_t* __restrict__ out) {
  int idx = blockIdx.x * 256 + threadIdx.x;
  const float* wp = w + (long)idx * 9;
  const float* mp = msk + (long)idx * 9;
#pragma unroll
  for (int khw = 0; khw < 9; ++khw)
    out[khw * 65536 + idx] = (bf16_t)(wp[khw] * mp[khw]);
}

// ---------------- zero only the pad borders of both intermediates ----------------
__global__ __launch_bounds__(256) void zero_borders_k(bf16_t* __restrict__ t0p,
                                                      bf16_t* __restrict__ t1p) {
  const int bid = blockIdx.x;               // 128: image n = bid>>1, buffer = bid&1
  bf16_t* base = ((bid & 1) ? t1p : t0p) + (long)(bid >> 1) * PLANE * CCH;
  for (int i = threadIdx.x; i < 132 * 32; i += 256) {
    int pix = i >> 5, c16 = i & 31;
    int r, col;
    if (pix < 34)       { r = 0;           col = pix; }
    else if (pix < 68)  { r = 33;          col = pix - 34; }
    else if (pix < 100) { r = pix - 68 + 1; col = 0; }
    else                { r = pix - 100 + 1; col = 33; }
    *(f32x4*)&base[(r * HP + col) * CCH + c16 * 8] = f32x4{0.f, 0.f, 0.f, 0.f};
  }
}

// ------- relu(bn1(x)) -> bf16, NCHW -> channels-last padded [n][34*34][256] -------
__global__ __launch_bounds__(256) void prep_input_k(const float* __restrict__ x,
                                                    const float* __restrict__ prm,
                                                    bf16_t* __restrict__ t0p) {
  __shared__ __align__(16) bf16_t tile[64 * 256];
  const int tid = threadIdx.x;
  const int bid = blockIdx.x;
  const int n   = bid >> 4;
  const int p0  = (bid & 15) << 6;
  const int px    = tid & 63;
  const int cbase = tid >> 6;
  for (int r = 0; r < 64; ++r) {
    int ci = r * 4 + cbase;
    float v = x[((n * 256 + ci) << 10) + p0 + px];
    float y = fmaxf(v * prm[ci] + prm[256 + ci], 0.f);
    int byte = px * 512 + ((ci * 2) ^ ((px & 7) << 4));
    *(bf16_t*)((char*)tile + byte) = (bf16_t)y;
  }
  __syncthreads();
  for (int j = 0; j < 8; ++j) {
    int off  = j * 256 + tid;
    int pix  = off >> 5;
    int c16  = off & 31;
    int byte = pix * 512 + ((c16 * 16) ^ ((pix & 7) << 4));
    bf16x8 v = *(const bf16x8*)((char*)tile + byte);
    int p = p0 + pix;
    long gp = ((long)n * PLANE + ((p >> 5) + 1) * HP + (p & 31) + 1) * CCH + c16 * 8;
    *(bf16x8*)(t0p + gp) = v;
  }
}

// ---------------- implicit-GEMM 3x3 conv, tap reuse + counted-vmcnt pipeline ------
// K-order: 8 ci-chunks of 32 (outer) x 9 taps (inner) = 72 phases.
// A (weights) prefetched 4 phases ahead into 5 rotating buffers; B (6x34 pixel
// patch) staged once per ci-chunk, double-buffered, issued 4+ phases before use.
// Raw s_barrier + counted s_waitcnt vmcnt(N): loads stay in flight across
// barriers (never drain to 0 mid-loop). B-patch LDS is XOR-swizzled
// (slot = r*136 + cc*4 + ((k + (cc>>1))&3)) with inverse-permuted staging
// sources so ds_read_b128 spreads across all 8 bank quads.
template <int EPI>
__global__ __launch_bounds__(256, 2) void conv3x3_k(const bf16_t* __restrict__ inp,
                                                    const bf16_t* __restrict__ wts,
                                                    const float* __restrict__ prm,
                                                    const float* __restrict__ resid,
                                                    bf16_t* __restrict__ out_cl,
                                                    float* __restrict__ out_f) {
  __shared__ __align__(128) bf16_t As[5][4096];   // 5 x 8 KB weight tiles [co128][ci32]
  __shared__ __align__(128) bf16_t Bs[2][8192];   // 2 x 16 KB pixel patches (816 granules)

  const int tid  = threadIdx.x;
  const int lane = tid & 63;
  const int wid  = tid >> 6;
  const int wm   = wid >> 1;
  const int wn   = wid & 1;

  const int bid = blockIdx.x;                  // 1024 = 8 XCDs * 128
  const int w   = ((bid & 7) << 7) + (bid >> 3);
  const int co0 = (w & 1) << 7;
  const int pt  = w >> 1;                      // 512 pixel tiles
  const int n   = pt >> 3;
  const int hb  = (pt & 7) << 2;               // padded input rows hb..hb+5 staged

  const int swz8 = (((lane & 3) ^ ((lane >> 2) & 3) ^ (lane >> 4)) << 3);
  const int l15  = lane & 15;
  const int k4   = lane >> 4;

  f32x4 acc[4][4];
#pragma unroll
  for (int i = 0; i < 4; ++i)
#pragma unroll
    for (int j = 0; j < 4; ++j) acc[i][j] = f32x4{0.f, 0.f, 0.f, 0.f};

  auto stageA = [&](int abuf, int c, int t) {   // 2 loads/thread
    const int ci0 = c << 5;
#pragma unroll
    for (int j = 0; j < 2; ++j) {
      const int ch  = wid * 2 + j;
      const int row = ch * 16 + (lane >> 2);
      const bf16_t* ga = wts + ((t * CCH + co0 + row) * CCH + ci0 + swz8);
      __builtin_amdgcn_global_load_lds((const AS_GLOBAL void*)ga,
                                       (AS_LDS void*)(&As[abuf][ch * 512]), 16, 0, 0);
    }
  };

  auto stageB = [&](int bbuf, int c) {          // 4 loads/thread
    const int ci0 = c << 5;
#pragma unroll
    for (int j = 0; j < 4; ++j) {
      const int ibase = wid * 4 + j;
      int s = (ibase << 6) + lane;              // linear LDS slot this lane fills
      if (s > 815) s = 815;                     // tail slack, never read
      const int r     = s / 136;
      const int rem   = s - r * 136;
      const int cc    = rem >> 2;
      const int k     = ((rem & 3) - (cc >> 1)) & 3;  // inverse of read swizzle
      const bf16_t* gb = inp + ((n * PLANE + (hb + r) * HP + cc) * CCH + ci0 + (k << 3));
      __builtin_amdgcn_global_load_lds((const AS_GLOBAL void*)gb,
                                       (AS_LDS void*)(&Bs[bbuf][ibase * 512]), 16, 0, 0);
    }
  };

  auto compute = [&](int abuf, int bbuf, int kh, int kw) {
    bf16x8 av[4], bv[4];
#pragma unroll
    for (int mi = 0; mi < 4; ++mi)
      av[mi] = *(const bf16x8*)&As[abuf][((wm * 64 + mi * 16 + l15) << 5) + swz8];
#pragma unroll
    for (int ni = 0; ni < 4; ++ni) {
      const int p    = (wn << 6) + (ni << 4) + l15;
      const int cc   = (p & 31) + kw;
      const int slot = ((p >> 5) + kh) * 136 + (cc << 2) + ((k4 + (cc >> 1)) & 3);
      bv[ni] = *(const bf16x8*)&Bs[bbuf][slot << 3];
    }
#pragma unroll
    for (int mi = 0; mi < 4; ++mi)
#pragma unroll
      for (int ni = 0; ni < 4; ++ni)
        acc[mi][ni] = __builtin_amdgcn_mfma_f32_16x16x32_bf16(av[mi], bv[ni], acc[mi][ni], 0, 0, 0);
  };

  // prologue: B chunk0 + A phases 0..3
  stageB(0, 0);
  stageA(0, 0, 0); stageA(1, 0, 1); stageA(2, 0, 2); stageA(3, 0, 3);

  int ab = 0;                                   // A-buffer of current phase (p % 5)
  for (int c = 0; c < 7; ++c) {
#pragma unroll
    for (int t = 0; t < 9; ++t) {
      // wait for this phase's A (and, at t==0, this chunk's B — older, implied);
      // N = loads issued after it (derivation in journal): 6 steady, 10 while
      // next-chunk B is younger than the awaited A.
      if (t >= 1 && t <= 3) { VMW(10); } else { VMW(6); }
      __builtin_amdgcn_s_barrier();
      if (t == 0) stageB((c + 1) & 1, c + 1);
      int aw = ab + 4; if (aw >= 5) aw -= 5;
      if (t < 5) stageA(aw, c, t + 4);
      else       stageA(aw, c + 1, t - 5);
      compute(ab, c & 1, t / 3, t % 3);
      ++ab; if (ab == 5) ab = 0;
    }
  }
  // last chunk (c == 7): no B prefetch, A issues stop at phase 71
#pragma unroll
  for (int t = 0; t < 9; ++t) {
    if      (t == 6) { VMW(4); }
    else if (t == 7) { VMW(2); }
    else if (t == 8) { VMW(0); }
    else             { VMW(6); }
    __builtin_amdgcn_s_barrier();
    if (t < 5) { int aw = ab + 4; if (aw >= 5) aw -= 5; stageA(aw, 7, t + 4); }
    compute(ab, 1, t / 3, t % 3);
    ++ab; if (ab == 5) ab = 0;
  }

  // C/D layout: col(pixel) = lane&15, row(co) = (lane>>4)*4 + reg
  if (EPI == 0) {
#pragma unroll
    for (int mi = 0; mi < 4; ++mi) {
      const int co_b = co0 + wm * 64 + mi * 16 + ((lane >> 4) << 2);
      const float s0 = prm[co_b], s1 = prm[co_b + 1], s2 = prm[co_b + 2], s3 = prm[co_b + 3];
      const float t0 = prm[256 + co_b], t1 = prm[256 + co_b + 1],
                  t2 = prm[256 + co_b + 2], t3 = prm[256 + co_b + 3];
#pragma unroll
      for (int ni = 0; ni < 4; ++ni) {
        f32x4 v = acc[mi][ni];
        const int p  = (wn << 6) + (ni << 4) + l15;
        const int pr = p >> 5, pc = p & 31;
        bf16x4 pk;
        pk[0] = (bf16_t)fmaxf(v[0] * s0 + t0, 0.f);
        pk[1] = (bf16_t)fmaxf(v[1] * s1 + t1, 0.f);
        pk[2] = (bf16_t)fmaxf(v[2] * s2 + t2, 0.f);
        pk[3] = (bf16_t)fmaxf(v[3] * s3 + t3, 0.f);
        *(bf16x4*)&out_cl[(n * PLANE + (hb + pr + 1) * HP + pc + 1) * CCH + co_b] = pk;
      }
    }
  } else {
#pragma unroll
    for (int mi = 0; mi < 4; ++mi) {
      const int co_b = co0 + wm * 64 + mi * 16 + ((lane >> 4) << 2);
#pragma unroll
      for (int ni = 0; ni < 4; ++ni) {
        f32x4 v = acc[mi][ni];
        const int p  = (wn << 6) + (ni << 4) + l15;
        const int gp = ((n * CCH + co_b) << 10) + (hb << 5) + p;
        out_f[gp]        = v[0] + resid[gp];
        out_f[gp + 1024] = v[1] + resid[gp + 1024];
        out_f[gp + 2048] = v[2] + resid[gp + 2048];
        out_f[gp + 3072] = v[3] + resid[gp + 3072];
      }
    }
  }
}

extern "C" void kernel_launch(void* const* d_in, const int* in_sizes, int n_in,
                              void* d_out, int out_size, void* d_ws, size_t ws_size,
                              hipStream_t stream) {
  const float* x  = (const float*)d_in[0];
  const float* g1 = (const float*)d_in[1];
  const float* b1 = (const float*)d_in[2];
  const float* m1 = (const float*)d_in[3];
  const float* v1 = (const float*)d_in[4];
  const float* w1 = (const float*)d_in[5];
  const float* k1 = (const float*)d_in[6];
  const float* g2 = (const float*)d_in[7];
  const float* b2 = (const float*)d_in[8];
  const float* m2 = (const float*)d_in[9];
  const float* v2 = (const float*)d_in[10];
  const float* w2 = (const float*)d_in[11];
  const float* k2 = (const float*)d_in[12];

  char* ws = (char*)d_ws;
  const size_t T0P_B = (size_t)64 * PLANE * CCH * 2;
  bf16_t* t0p = (bf16_t*)ws;
  bf16_t* t1p = (bf16_t*)(ws + T0P_B);
  bf16_t* mw1 = (bf16_t*)(ws + 2 * T0P_B);
  bf16_t* mw2 = (bf16_t*)(ws + 2 * T0P_B + 1179648);
  float*  prm = (float*)(ws + 2 * T0P_B + 2 * 1179648);

  prep_params_k<<<1, 256, 0, stream>>>(g1, b1, m1, v1, g2, b2, m2, v2, prm);
  zero_borders_k<<<128, 256, 0, stream>>>(t0p, t1p);
  prep_weights_k<<<256, 256, 0, stream>>>(w1, k1, mw1);
  prep_weights_k<<<256, 256, 0, stream>>>(w2, k2, mw2);
  prep_input_k<<<1024, 256, 0, stream>>>(x, prm, t0p);

  conv3x3_k<0><<<1024, 256, 0, stream>>>(t0p, mw1, prm + 512, nullptr, t1p, nullptr);
  conv3x3_k<1><<<1024, 256, 0, stream>>>(t1p, mw2, nullptr, x, nullptr, (float*)d_out);
}

// Round 4
// 192.931 us; speedup vs baseline: 1.0535x; 1.0535x over previous
//
#include <hip/hip_runtime.h>
#include <hip/hip_bf16.h>
#include <stdint.h>

typedef __bf16 bf16_t;
typedef __bf16 bf16x8 __attribute__((ext_vector_type(8)));
typedef __bf16 bf16x4 __attribute__((ext_vector_type(4)));
typedef float  f32x4  __attribute__((ext_vector_type(4)));

#define AS_GLOBAL __attribute__((address_space(1)))
#define AS_LDS    __attribute__((address_space(3)))
#define VMW(N) asm volatile("s_waitcnt vmcnt(" #N ")" ::: "memory")

static constexpr int CCH   = 256;
static constexpr int HP    = 34;
static constexpr int PLANE = HP * HP;   // 1156 padded pixels per image

// ---------------- BN parameter folding ----------------
__global__ void prep_params_k(const float* g1, const float* b1, const float* m1, const float* v1,
                              const float* g2, const float* b2, const float* m2, const float* v2,
                              float* prm) {
  int i = threadIdx.x;
  float i1 = g1[i] * rsqrtf(v1[i] + 1e-5f);
  prm[i]       = i1;
  prm[256 + i] = b1[i] - m1[i] * i1;
  float i2 = g2[i] * rsqrtf(v2[i] + 1e-5f);
  prm[512 + i] = i2;
  prm[768 + i] = b2[i] - m2[i] * i2;
}

// ---------------- masked weights -> bf16, [khw][co][ci] ----------------
__global__ __launch_bounds__(256) void prep_weights_k(const float* __restrict__ w,
                                                      const float* __restrict__ msk,
                                                      bf16_t* __restrict__ out) {
  int idx = blockIdx.x * 256 + threadIdx.x;
  const float* wp = w + (long)idx * 9;
  const float* mp = msk + (long)idx * 9;
#pragma unroll
  for (int khw = 0; khw < 9; ++khw)
    out[khw * 65536 + idx] = (bf16_t)(wp[khw] * mp[khw]);
}

// ---------------- zero only the pad borders of both intermediates ----------------
__global__ __launch_bounds__(256) void zero_borders_k(bf16_t* __restrict__ t0p,
                                                      bf16_t* __restrict__ t1p) {
  const int bid = blockIdx.x;               // 128: image n = bid>>1, buffer = bid&1
  bf16_t* base = ((bid & 1) ? t1p : t0p) + (long)(bid >> 1) * PLANE * CCH;
  for (int i = threadIdx.x; i < 132 * 32; i += 256) {
    int pix = i >> 5, c16 = i & 31;
    int r, col;
    if (pix < 34)       { r = 0;           col = pix; }
    else if (pix < 68)  { r = 33;          col = pix - 34; }
    else if (pix < 100) { r = pix - 68 + 1; col = 0; }
    else                { r = pix - 100 + 1; col = 33; }
    *(f32x4*)&base[(r * HP + col) * CCH + c16 * 8] = f32x4{0.f, 0.f, 0.f, 0.f};
  }
}

// ------- relu(bn1(x)) -> bf16, NCHW -> channels-last padded [n][34*34][256] -------
__global__ __launch_bounds__(256) void prep_input_k(const float* __restrict__ x,
                                                    const float* __restrict__ prm,
                                                    bf16_t* __restrict__ t0p) {
  __shared__ __align__(16) bf16_t tile[64 * 256];
  const int tid = threadIdx.x;
  const int bid = blockIdx.x;
  const int n   = bid >> 4;
  const int p0  = (bid & 15) << 6;
  const int px    = tid & 63;
  const int cbase = tid >> 6;
  for (int r = 0; r < 64; ++r) {
    int ci = r * 4 + cbase;
    float v = x[((n * 256 + ci) << 10) + p0 + px];
    float y = fmaxf(v * prm[ci] + prm[256 + ci], 0.f);
    int byte = px * 512 + ((ci * 2) ^ ((px & 7) << 4));
    *(bf16_t*)((char*)tile + byte) = (bf16_t)y;
  }
  __syncthreads();
  for (int j = 0; j < 8; ++j) {
    int off  = j * 256 + tid;
    int pix  = off >> 5;
    int c16  = off & 31;
    int byte = pix * 512 + ((c16 * 16) ^ ((pix & 7) << 4));
    bf16x8 v = *(const bf16x8*)((char*)tile + byte);
    int p = p0 + pix;
    long gp = ((long)n * PLANE + ((p >> 5) + 1) * HP + (p & 31) + 1) * CCH + c16 * 8;
    *(bf16x8*)(t0p + gp) = v;
  }
}

// ---------------- implicit-GEMM 3x3 conv: tap reuse + register-pipelined phases ---
// 72 phases = 8 ci-chunks x 9 taps. A prefetched 4 phases ahead (5 bufs); B patch
// per ci-chunk (2 bufs). NEW: fragment double-buffering in registers — at phase p
// the ds_reads for phase p+1 are issued into the alternate frag set, then
// lgkmcnt(8) waits only on phase p's frags, so LDS latency overlaps the MFMA
// cluster. Frag sets alternate by compile-time phase parity (no runtime reg
// indexing). vmcnt schedule covers A(p) AND A(p+1) before each barrier:
// steady VMW(4); VMW(8) at t=1,2 (B(c+1) in queue); tail 4/4/4/4/4/4/2/0/0.
template <int EPI>
__global__ __launch_bounds__(256, 2) void conv3x3_k(const bf16_t* __restrict__ inp,
                                                    const bf16_t* __restrict__ wts,
                                                    const float* __restrict__ prm,
                                                    const float* __restrict__ resid,
                                                    bf16_t* __restrict__ out_cl,
                                                    float* __restrict__ out_f) {
  __shared__ __align__(128) bf16_t As[5][4096];   // 5 x 8 KB weight tiles [co128][ci32]
  __shared__ __align__(128) bf16_t Bs[2][8192];   // 2 x 16 KB pixel patches (816 granules)

  const int tid  = threadIdx.x;
  const int lane = tid & 63;
  const int wid  = tid >> 6;
  const int wm   = wid >> 1;
  const int wn   = wid & 1;

  const int bid = blockIdx.x;                  // 1024 = 8 XCDs * 128
  const int w   = ((bid & 7) << 7) + (bid >> 3);
  const int co0 = (w & 1) << 7;
  const int pt  = w >> 1;                      // 512 pixel tiles
  const int n   = pt >> 3;
  const int hb  = (pt & 7) << 2;               // padded input rows hb..hb+5 staged

  const int swz8 = (((lane & 3) ^ ((lane >> 2) & 3) ^ (lane >> 4)) << 3);
  const int l15  = lane & 15;
  const int k4   = lane >> 4;

  f32x4 acc[4][4];
#pragma unroll
  for (int i = 0; i < 4; ++i)
#pragma unroll
    for (int j = 0; j < 4; ++j) acc[i][j] = f32x4{0.f, 0.f, 0.f, 0.f};

  bf16x8 avA[4], bvA[4], avB[4], bvB[4];       // two fragment sets (phase parity)

  auto stageA = [&](int abuf, int c, int t) {   // 2 loads/thread
    const int ci0 = c << 5;
#pragma unroll
    for (int j = 0; j < 2; ++j) {
      const int ch  = wid * 2 + j;
      const int row = ch * 16 + (lane >> 2);
      const bf16_t* ga = wts + ((t * CCH + co0 + row) * CCH + ci0 + swz8);
      __builtin_amdgcn_global_load_lds((const AS_GLOBAL void*)ga,
                                       (AS_LDS void*)(&As[abuf][ch * 512]), 16, 0, 0);
    }
  };

  auto stageB = [&](int bbuf, int c) {          // 4 loads/thread
    const int ci0 = c << 5;
#pragma unroll
    for (int j = 0; j < 4; ++j) {
      const int ibase = wid * 4 + j;
      int s = (ibase << 6) + lane;
      if (s > 815) s = 815;                     // tail slack, never read
      const int r     = s / 136;
      const int rem   = s - r * 136;
      const int cc    = rem >> 2;
      const int k     = ((rem & 3) - (cc >> 1)) & 3;  // inverse of read swizzle
      const bf16_t* gb = inp + ((n * PLANE + (hb + r) * HP + cc) * CCH + ci0 + (k << 3));
      __builtin_amdgcn_global_load_lds((const AS_GLOBAL void*)gb,
                                       (AS_LDS void*)(&Bs[bbuf][ibase * 512]), 16, 0, 0);
    }
  };

#define PREF(AV, BV, ABUF, BB, KH, KW) do {                                        \
    _Pragma("unroll") for (int mi = 0; mi < 4; ++mi)                               \
      AV[mi] = *(const bf16x8*)&As[ABUF][((wm * 64 + mi * 16 + l15) << 5) + swz8]; \
    _Pragma("unroll") for (int ni = 0; ni < 4; ++ni) {                             \
      const int p_    = (wn << 6) + (ni << 4) + l15;                               \
      const int cc_   = (p_ & 31) + (KW);                                          \
      const int slot_ = ((p_ >> 5) + (KH)) * 136 + (cc_ << 2) + ((k4 + (cc_ >> 1)) & 3); \
      BV[ni] = *(const bf16x8*)&Bs[BB][slot_ << 3];                                \
    }                                                                              \
  } while (0)

#define MFMA16(AV, BV) do {                                                        \
    _Pragma("unroll") for (int mi = 0; mi < 4; ++mi)                               \
    _Pragma("unroll") for (int ni = 0; ni < 4; ++ni)                               \
      acc[mi][ni] = __builtin_amdgcn_mfma_f32_16x16x32_bf16(AV[mi], BV[ni], acc[mi][ni], 0, 0, 0); \
  } while (0)

  // one phase. t, PAR, LAST are literals; c is runtime. ab == p%5 maintained.
#define PH(t, PAR, c, LAST) do {                                                   \
    if ((LAST) && (t) >= 6) { if ((t) == 6) { VMW(2); } else { VMW(0); } }         \
    else if (!(LAST) && ((t) == 1 || (t) == 2)) { VMW(8); }                        \
    else { VMW(4); }                                                               \
    __builtin_amdgcn_s_barrier();                                                  \
    if (!(LAST) && (t) == 0) stageB(((c) + 1) & 1, (c) + 1);                       \
    {                                                                              \
      int aw = ab + 4; if (aw >= 5) aw -= 5;                                       \
      if (!(LAST)) { if ((t) < 5) stageA(aw, (c), (t) + 4);                        \
                     else         stageA(aw, (c) + 1, (t) - 5); }                  \
      else if ((t) < 5) stageA(aw, 7, (t) + 4);                                    \
    }                                                                              \
    if (!((LAST) && (t) == 8)) {                                                   \
      int ab1 = ab + 1; if (ab1 >= 5) ab1 -= 5;                                    \
      const int bb1 = ((t) < 8 ? (c) & 1 : ((c) + 1) & 1);                         \
      constexpr int T1 = ((t) + 1) % 9;                                            \
      if (((PAR) + (t)) & 1) { PREF(avA, bvA, ab1, bb1, T1 / 3, T1 % 3); }         \
      else                   { PREF(avB, bvB, ab1, bb1, T1 / 3, T1 % 3); }         \
      asm volatile("s_waitcnt lgkmcnt(8)" ::: "memory");                           \
    } else {                                                                       \
      asm volatile("s_waitcnt lgkmcnt(0)" ::: "memory");                           \
    }                                                                              \
    __builtin_amdgcn_sched_barrier(0);                                             \
    __builtin_amdgcn_s_setprio(1);                                                 \
    if (((PAR) + (t)) & 1) { MFMA16(avB, bvB); } else { MFMA16(avA, bvA); }        \
    __builtin_amdgcn_s_setprio(0);                                                 \
    ++ab; if (ab == 5) ab = 0;                                                     \
  } while (0)

#define CHUNK(PAR, c) do {                                                         \
    PH(0, PAR, c, 0); PH(1, PAR, c, 0); PH(2, PAR, c, 0);                          \
    PH(3, PAR, c, 0); PH(4, PAR, c, 0); PH(5, PAR, c, 0);                          \
    PH(6, PAR, c, 0); PH(7, PAR, c, 0); PH(8, PAR, c, 0);                          \
  } while (0)

  // prologue: B chunk0 + A taps 0..3; wait leaves A@2,A@3 in flight (VMW(6))
  stageB(0, 0);
  stageA(0, 0, 0); stageA(1, 0, 1); stageA(2, 0, 2); stageA(3, 0, 3);
  VMW(6);
  __builtin_amdgcn_s_barrier();
  PREF(avA, bvA, 0, 0, 0, 0);                  // frags for phase 0 (set A)

  int ab = 0;
  CHUNK(0, 0); CHUNK(1, 1); CHUNK(0, 2); CHUNK(1, 3);
  CHUNK(0, 4); CHUNK(1, 5); CHUNK(0, 6);
  // tail chunk c=7 (PAR=1)
  PH(0, 1, 7, 1); PH(1, 1, 7, 1); PH(2, 1, 7, 1); PH(3, 1, 7, 1); PH(4, 1, 7, 1);
  PH(5, 1, 7, 1); PH(6, 1, 7, 1); PH(7, 1, 7, 1); PH(8, 1, 7, 1);

#undef PH
#undef CHUNK
#undef PREF
#undef MFMA16

  // C/D layout: col(pixel) = lane&15, row(co) = (lane>>4)*4 + reg
  if (EPI == 0) {
#pragma unroll
    for (int mi = 0; mi < 4; ++mi) {
      const int co_b = co0 + wm * 64 + mi * 16 + ((lane >> 4) << 2);
      const float s0 = prm[co_b], s1 = prm[co_b + 1], s2 = prm[co_b + 2], s3 = prm[co_b + 3];
      const float t0 = prm[256 + co_b], t1 = prm[256 + co_b + 1],
                  t2 = prm[256 + co_b + 2], t3 = prm[256 + co_b + 3];
#pragma unroll
      for (int ni = 0; ni < 4; ++ni) {
        f32x4 v = acc[mi][ni];
        const int p  = (wn << 6) + (ni << 4) + l15;
        const int pr = p >> 5, pc = p & 31;
        bf16x4 pk;
        pk[0] = (bf16_t)fmaxf(v[0] * s0 + t0, 0.f);
        pk[1] = (bf16_t)fmaxf(v[1] * s1 + t1, 0.f);
        pk[2] = (bf16_t)fmaxf(v[2] * s2 + t2, 0.f);
        pk[3] = (bf16_t)fmaxf(v[3] * s3 + t3, 0.f);
        *(bf16x4*)&out_cl[(n * PLANE + (hb + pr + 1) * HP + pc + 1) * CCH + co_b] = pk;
      }
    }
  } else {
#pragma unroll
    for (int mi = 0; mi < 4; ++mi) {
      const int co_b = co0 + wm * 64 + mi * 16 + ((lane >> 4) << 2);
#pragma unroll
      for (int ni = 0; ni < 4; ++ni) {
        f32x4 v = acc[mi][ni];
        const int p  = (wn << 6) + (ni << 4) + l15;
        const int gp = ((n * CCH + co_b) << 10) + (hb << 5) + p;
        out_f[gp]        = v[0] + resid[gp];
        out_f[gp + 1024] = v[1] + resid[gp + 1024];
        out_f[gp + 2048] = v[2] + resid[gp + 2048];
        out_f[gp + 3072] = v[3] + resid[gp + 3072];
      }
    }
  }
}

extern "C" void kernel_launch(void* const* d_in, const int* in_sizes, int n_in,
                              void* d_out, int out_size, void* d_ws, size_t ws_size,
                              hipStream_t stream) {
  const float* x  = (const float*)d_in[0];
  const float* g1 = (const float*)d_in[1];
  const float* b1 = (const float*)d_in[2];
  const float* m1 = (const float*)d_in[3];
  const float* v1 = (const float*)d_in[4];
  const float* w1 = (const float*)d_in[5];
  const float* k1 = (const float*)d_in[6];
  const float* g2 = (const float*)d_in[7];
  const float* b2 = (const float*)d_in[8];
  const float* m2 = (const float*)d_in[9];
  const float* v2 = (const float*)d_in[10];
  const float* w2 = (const float*)d_in[11];
  const float* k2 = (const float*)d_in[12];

  char* ws = (char*)d_ws;
  const size_t T0P_B = (size_t)64 * PLANE * CCH * 2;
  bf16_t* t0p = (bf16_t*)ws;
  bf16_t* t1p = (bf16_t*)(ws + T0P_B);
  bf16_t* mw1 = (bf16_t*)(ws + 2 * T0P_B);
  bf16_t* mw2 = (bf16_t*)(ws + 2 * T0P_B + 1179648);
  float*  prm = (float*)(ws + 2 * T0P_B + 2 * 1179648);

  prep_params_k<<<1, 256, 0, stream>>>(g1, b1, m1, v1, g2, b2, m2, v2, prm);
  zero_borders_k<<<128, 256, 0, stream>>>(t0p, t1p);
  prep_weights_k<<<256, 256, 0, stream>>>(w1, k1, mw1);
  prep_weights_k<<<256, 256, 0, stream>>>(w2, k2, mw2);
  prep_input_k<<<1024, 256, 0, stream>>>(x, prm, t0p);

  conv3x3_k<0><<<1024, 256, 0, stream>>>(t0p, mw1, prm + 512, nullptr, t1p, nullptr);
  conv3x3_k<1><<<1024, 256, 0, stream>>>(t1p, mw2, nullptr, x, nullptr, (float*)d_out);
}